// Round 1
// baseline (249.747 us; speedup 1.0000x reference)
//
#include <hip/hip_runtime.h>
#include <cstdint>

#define C_    512
#define HW_   784
#define B_    64
#define BN_EPS 1e-5f

// Workspace layout:
//   [0, 32768)        : wbits   uint32[512][16]   (bit c%32 of word c/32 = 1 iff W[o][c] < 0)
//   [32768, 40960)    : params  float4[512]       {A, C0 = B2 - pr_shift, slope, bias}
//
// Math folding:
//   scale[o] = mean|W[o,:]| ; S = 512 - 2*popcount_xor ; y = scale*S
//   bn = gamma*(y-mean)*rsqrt(var+eps)+beta = A*S + B2,  A = gamma*scale*r, B2 = beta - gamma*mean*r
//   t  = bn + x - shift = A*S + (B2 - shift) + x
//   out = (t>0 ? t : slope*t) + bias

__global__ __launch_bounds__(64) void precompute_kernel(
    const float* __restrict__ W,
    const float* __restrict__ bn_gamma, const float* __restrict__ bn_beta,
    const float* __restrict__ bn_mean,  const float* __restrict__ bn_var,
    const float* __restrict__ pr_slope, const float* __restrict__ pr_shift,
    const float* __restrict__ pr_bias,
    uint32_t* __restrict__ wbits, float4* __restrict__ params)
{
    const int o    = blockIdx.x;
    const int lane = threadIdx.x;
    const float* wrow = W + (size_t)o * C_;

    // mean(|W[o,:]|): stride-64 partials + wave-64 butterfly
    float s = 0.f;
    for (int c = lane; c < C_; c += 64) s += fabsf(wrow[c]);
    for (int off = 32; off > 0; off >>= 1) s += __shfl_down(s, off, 64);

    // sign bits: lanes 0..15 each pack one 32-bit word
    if (lane < 16) {
        uint32_t m = 0;
        const int cbase = lane * 32;
        for (int t = 0; t < 32; ++t) {
            if (wrow[cbase + t] < 0.f) m |= (1u << t);
        }
        wbits[o * 16 + lane] = m;
    }

    if (lane == 0) {
        float scale = s * (1.0f / (float)C_);
        float r  = rsqrtf(bn_var[o] + BN_EPS);
        float A  = bn_gamma[o] * scale * r;
        float B2 = bn_beta[o] - bn_gamma[o] * bn_mean[o] * r;
        params[o] = make_float4(A, B2 - pr_shift[o], pr_slope[o], pr_bias[o]);
    }
}

__global__ __launch_bounds__(256) void fused_kernel(
    const float* __restrict__ x, const float* __restrict__ rsign_bias,
    const uint32_t* __restrict__ wbits, const float4* __restrict__ params,
    float* __restrict__ out)
{
    // a-bit tile: 64 hw rows x 16 words, stride 17 to break bank conflicts
    __shared__ uint32_t abits[64 * 17];

    const int i  = threadIdx.x;                                   // hw lane (0..63)
    const int jj = __builtin_amdgcn_readfirstlane(threadIdx.y);   // wave-uniform group (0..3)
    const int b  = blockIdx.y;
    const int hw = blockIdx.x * 64 + i;
    const bool valid = (hw < HW_);

    const float* xb = x + (size_t)b * C_ * HW_;

    // ---- Phase 1: binarize channels [128*jj, 128*jj+128) for this hw lane ----
    if (valid) {
        const int c0 = jj * 128;
        #pragma unroll
        for (int wq = 0; wq < 4; ++wq) {
            uint32_t m = 0;
            const int cbase = c0 + wq * 32;
            #pragma unroll
            for (int t = 0; t < 32; ++t) {
                const int c = cbase + t;                 // wave-uniform
                float v = xb[(size_t)c * HW_ + hw] + rsign_bias[c];
                if (v < 0.f) m |= (1u << t);
            }
            abits[i * 17 + jj * 4 + wq] = m;
        }
    }
    __syncthreads();
    if (!valid) return;

    // ---- Phase 2: own full 512-bit activation row in registers ----
    uint32_t a[16];
    #pragma unroll
    for (int w = 0; w < 16; ++w) a[w] = abits[i * 17 + w];

    float* ob = out + (size_t)b * C_ * HW_;
    const int obase = jj * 128;                          // wave-uniform

    for (int oo = 0; oo < 128; ++oo) {
        const int o = obase + oo;                        // wave-uniform
        const uint32_t* wr = wbits + o * 16;
        int P = 0;
        #pragma unroll
        for (int w = 0; w < 16; ++w) P += __popc(a[w] ^ wr[w]);

        const float4 p = params[o];
        const float Sf = (float)(C_ - 2 * P);
        float t = fmaf(p.x, Sf, p.y) + xb[(size_t)o * HW_ + hw];
        float r = (t > 0.f ? t : p.z * t) + p.w;
        ob[(size_t)o * HW_ + hw] = r;
    }
}

extern "C" void kernel_launch(void* const* d_in, const int* in_sizes, int n_in,
                              void* d_out, int out_size, void* d_ws, size_t ws_size,
                              hipStream_t stream) {
    const float* x          = (const float*)d_in[0];
    const float* rsign_bias = (const float*)d_in[1];
    const float* W          = (const float*)d_in[2];
    const float* bn_gamma   = (const float*)d_in[3];
    const float* bn_beta    = (const float*)d_in[4];
    const float* bn_mean    = (const float*)d_in[5];
    const float* bn_var     = (const float*)d_in[6];
    const float* pr_slope   = (const float*)d_in[7];
    const float* pr_shift   = (const float*)d_in[8];
    const float* pr_bias    = (const float*)d_in[9];
    float* out = (float*)d_out;

    uint32_t* wbits = (uint32_t*)d_ws;
    float4*   params = (float4*)((char*)d_ws + 32768);

    precompute_kernel<<<dim3(C_), dim3(64), 0, stream>>>(
        W, bn_gamma, bn_beta, bn_mean, bn_var, pr_slope, pr_shift, pr_bias,
        wbits, params);

    // 784 = 12*64 + 16 -> 13 hw tiles of 64 (last partial), 64 batch images
    fused_kernel<<<dim3(13, B_), dim3(64, 4), 0, stream>>>(
        x, rsign_bias, wbits, params, out);
}

// Round 2
// 240.835 us; speedup vs baseline: 1.0370x; 1.0370x over previous
//
#include <hip/hip_runtime.h>
#include <cstdint>

#define C_    512
#define HW_   784
#define B_    64
#define BN_EPS 1e-5f

// Workspace layout:
//   [0, 32768)        : wbits   uint32[512][16]   (bit c%32 of word c/32 = 1 iff W[o][c] < 0)
//   [32768, 40960)    : params  float4[512]       {A, C0 = B2 - pr_shift, slope, bias}
//
// Math folding:
//   scale[o] = mean|W[o,:]| ; S = 512 - 2*popcount_xor ; y = scale*S
//   bn = gamma*(y-mean)*rsqrt(var+eps)+beta = A*S + B2,  A = gamma*scale*r, B2 = beta - gamma*mean*r
//   t  = bn + x - shift = A*S + (B2 - shift) + x
//   out = (t>0 ? t : slope*t) + bias

__global__ __launch_bounds__(64) void precompute_kernel(
    const float* __restrict__ W,
    const float* __restrict__ bn_gamma, const float* __restrict__ bn_beta,
    const float* __restrict__ bn_mean,  const float* __restrict__ bn_var,
    const float* __restrict__ pr_slope, const float* __restrict__ pr_shift,
    const float* __restrict__ pr_bias,
    uint32_t* __restrict__ wbits, float4* __restrict__ params)
{
    const int o    = blockIdx.x;
    const int lane = threadIdx.x;
    const float* wrow = W + (size_t)o * C_;

    // mean(|W[o,:]|): stride-64 partials + wave-64 butterfly
    float s = 0.f;
    for (int c = lane; c < C_; c += 64) s += fabsf(wrow[c]);
    for (int off = 32; off > 0; off >>= 1) s += __shfl_down(s, off, 64);

    // sign bits: lanes 0..15 each pack one 32-bit word
    if (lane < 16) {
        uint32_t m = 0;
        const int cbase = lane * 32;
        #pragma unroll
        for (int t = 0; t < 32; ++t) {
            if (wrow[cbase + t] < 0.f) m |= (1u << t);
        }
        wbits[o * 16 + lane] = m;
    }

    if (lane == 0) {
        float scale = s * (1.0f / (float)C_);
        float r  = rsqrtf(bn_var[o] + BN_EPS);
        float A  = bn_gamma[o] * scale * r;
        float B2 = bn_beta[o] - bn_gamma[o] * bn_mean[o] * r;
        params[o] = make_float4(A, B2 - pr_shift[o], pr_slope[o], pr_bias[o]);
    }
}

// Block: (64 hw-lanes) x (8 waves). Each wave owns 64 output channels and
// binarizes 64 input channels (2 bit-words) in phase 1. 832 blocks x 8 waves
// = 6656 waves -> ~81% of the 8192-wave device capacity (R1 was 40% max).
__global__ __launch_bounds__(512) void fused_kernel(
    const float* __restrict__ x, const float* __restrict__ rsign_bias,
    const uint32_t* __restrict__ wbits, const float4* __restrict__ params,
    float* __restrict__ out)
{
    // a-bit tile: 64 hw rows x 16 words, stride 17 -> 2-way bank aliasing (free)
    __shared__ uint32_t abits[64 * 17];

    const int i  = threadIdx.x;                                   // hw lane (0..63)
    const int jj = __builtin_amdgcn_readfirstlane(threadIdx.y);   // wave-uniform group (0..7)
    const int b  = blockIdx.y;
    const int hw = blockIdx.x * 64 + i;
    const bool valid = (hw < HW_);

    const float* xb = x + (size_t)b * C_ * HW_;

    // ---- Phase 1: binarize channels [64*jj, 64*jj+64) for this hw lane ----
    if (valid) {
        const int c0 = jj * 64;
        #pragma unroll
        for (int wq = 0; wq < 2; ++wq) {
            uint32_t m = 0;
            const int cbase = c0 + wq * 32;
            #pragma unroll
            for (int t = 0; t < 32; ++t) {
                const int c = cbase + t;                 // wave-uniform
                float v = xb[(size_t)c * HW_ + hw] + rsign_bias[c];
                if (v < 0.f) m |= (1u << t);
            }
            abits[i * 17 + jj * 2 + wq] = m;
        }
    }
    __syncthreads();
    if (!valid) return;

    // ---- Phase 2: own full 512-bit activation row in registers ----
    uint32_t a[16];
    #pragma unroll
    for (int w = 0; w < 16; ++w) a[w] = abits[i * 17 + w];

    float* ob = out + (size_t)b * C_ * HW_;
    const int obase = jj * 64;                           // wave-uniform

    #pragma unroll 2
    for (int oo = 0; oo < 64; ++oo) {
        const int o = obase + oo;                        // wave-uniform
        const uint32_t* wr = wbits + o * 16;
        int P = 0;
        #pragma unroll
        for (int w = 0; w < 16; ++w) P += __popc(a[w] ^ wr[w]);

        const float4 p = params[o];
        const float Sf = (float)(C_ - 2 * P);
        float t = fmaf(p.x, Sf, p.y) + xb[(size_t)o * HW_ + hw];
        float r = (t > 0.f ? t : p.z * t) + p.w;
        ob[(size_t)o * HW_ + hw] = r;
    }
}

extern "C" void kernel_launch(void* const* d_in, const int* in_sizes, int n_in,
                              void* d_out, int out_size, void* d_ws, size_t ws_size,
                              hipStream_t stream) {
    const float* x          = (const float*)d_in[0];
    const float* rsign_bias = (const float*)d_in[1];
    const float* W          = (const float*)d_in[2];
    const float* bn_gamma   = (const float*)d_in[3];
    const float* bn_beta    = (const float*)d_in[4];
    const float* bn_mean    = (const float*)d_in[5];
    const float* bn_var     = (const float*)d_in[6];
    const float* pr_slope   = (const float*)d_in[7];
    const float* pr_shift   = (const float*)d_in[8];
    const float* pr_bias    = (const float*)d_in[9];
    float* out = (float*)d_out;

    uint32_t* wbits = (uint32_t*)d_ws;
    float4*   params = (float4*)((char*)d_ws + 32768);

    precompute_kernel<<<dim3(C_), dim3(64), 0, stream>>>(
        W, bn_gamma, bn_beta, bn_mean, bn_var, pr_slope, pr_shift, pr_bias,
        wbits, params);

    // 784 = 12*64 + 16 -> 13 hw tiles of 64 (last partial), 64 batch images
    fused_kernel<<<dim3(13, B_), dim3(64, 8), 0, stream>>>(
        x, rsign_bias, wbits, params, out);
}

// Round 3
// 237.138 us; speedup vs baseline: 1.0532x; 1.0156x over previous
//
#include <hip/hip_runtime.h>
#include <cstdint>

#define C_    512
#define HW_   784
#define B_    64
#define BN_EPS 1e-5f

// Workspace layout:
//   [0, 32768)        : wbits   uint32[512][16]   (bit c%32 of word c/32 = 1 iff W[o][c] < 0)
//   [32768, 40960)    : params  float4[512]       {A, C0 = B2 - pr_shift, slope, bias}
//
// Math folding:
//   scale[o] = mean|W[o,:]| ; S = 512 - 2*popcount_xor ; y = scale*S
//   bn = gamma*(y-mean)*rsqrt(var+eps)+beta = A*S + B2,  A = gamma*scale*r, B2 = beta - gamma*mean*r
//   t  = bn + x - shift = A*S + (B2 - shift) + x
//   out = (t>0 ? t : slope*t) + bias

__global__ __launch_bounds__(64) void precompute_kernel(
    const float* __restrict__ W,
    const float* __restrict__ bn_gamma, const float* __restrict__ bn_beta,
    const float* __restrict__ bn_mean,  const float* __restrict__ bn_var,
    const float* __restrict__ pr_slope, const float* __restrict__ pr_shift,
    const float* __restrict__ pr_bias,
    uint32_t* __restrict__ wbits, float4* __restrict__ params)
{
    const int o    = blockIdx.x;
    const int lane = threadIdx.x;
    const float* wrow = W + (size_t)o * C_;

    // mean(|W[o,:]|): stride-64 partials + wave-64 butterfly
    float s = 0.f;
    for (int c = lane; c < C_; c += 64) s += fabsf(wrow[c]);
    for (int off = 32; off > 0; off >>= 1) s += __shfl_down(s, off, 64);

    // sign bits: lanes 0..15 each pack one 32-bit word
    if (lane < 16) {
        uint32_t m = 0;
        const int cbase = lane * 32;
        #pragma unroll
        for (int t = 0; t < 32; ++t) {
            if (wrow[cbase + t] < 0.f) m |= (1u << t);
        }
        wbits[o * 16 + lane] = m;
    }

    if (lane == 0) {
        float scale = s * (1.0f / (float)C_);
        float r  = rsqrtf(bn_var[o] + BN_EPS);
        float A  = bn_gamma[o] * scale * r;
        float B2 = bn_beta[o] - bn_gamma[o] * bn_mean[o] * r;
        params[o] = make_float4(A, B2 - pr_shift[o], pr_slope[o], pr_bias[o]);
    }
}

// Block: (64 hw-lanes) x (8 waves). Wave jj binarizes channels [64jj,64jj+64)
// AND computes outputs [64jj,64jj+64) -- the residual x-values it needs are
// exactly the ones it loads in phase 1, so they stay in registers (x_save[64],
// static indices under full unroll). Phase 2 has ZERO vector loads: wbits and
// params are wave-uniform (scalar loads), output stores are coalesced.
// __launch_bounds__(512,4): cap 128 VGPRs -> 2 blocks/CU = 16 waves/CU.
__global__ __launch_bounds__(512, 4) void fused_kernel(
    const float* __restrict__ x, const float* __restrict__ rsign_bias,
    const uint32_t* __restrict__ wbits, const float4* __restrict__ params,
    float* __restrict__ out)
{
    // a-bit tile: 64 hw rows x 16 words, stride 17 -> 2-way bank aliasing (free)
    __shared__ uint32_t abits[64 * 17];

    const int i  = threadIdx.x;                                   // hw lane (0..63)
    const int jj = __builtin_amdgcn_readfirstlane(threadIdx.y);   // wave-uniform group (0..7)
    const int b  = blockIdx.y;
    const int hw = blockIdx.x * 64 + i;
    const bool valid = (hw < HW_);

    const float* xb = x + (size_t)b * C_ * HW_;
    const int c0 = jj * 64;                                       // wave-uniform

    float x_save[64];   // this wave's channels = this wave's residuals

    // ---- Phase 1: binarize channels [c0, c0+64), keep x in registers ----
    if (valid) {
        #pragma unroll
        for (int wq = 0; wq < 2; ++wq) {
            uint32_t m = 0;
            #pragma unroll
            for (int t = 0; t < 32; ++t) {
                const int c = c0 + wq * 32 + t;          // wave-uniform
                const float xv = xb[(size_t)c * HW_ + hw];
                x_save[wq * 32 + t] = xv;
                if (xv + rsign_bias[c] < 0.f) m |= (1u << t);
            }
            abits[i * 17 + jj * 2 + wq] = m;
        }
    }
    __syncthreads();
    if (!valid) return;

    // ---- Phase 2: full 512-bit activation row from LDS, pure compute+store ----
    uint32_t a[16];
    #pragma unroll
    for (int w = 0; w < 16; ++w) a[w] = abits[i * 17 + w];

    float* ob = out + (size_t)b * C_ * HW_;

    #pragma unroll
    for (int oo = 0; oo < 64; ++oo) {
        const int o = c0 + oo;                           // wave-uniform
        const uint32_t* wr = wbits + o * 16;
        int P = 0;
        #pragma unroll
        for (int w = 0; w < 16; ++w) P += __popc(a[w] ^ wr[w]);

        const float4 p = params[o];
        const float Sf = (float)(C_ - 2 * P);
        float t = fmaf(p.x, Sf, p.y) + x_save[oo];
        float r = (t > 0.f ? t : p.z * t) + p.w;
        ob[(size_t)o * HW_ + hw] = r;
    }
}

extern "C" void kernel_launch(void* const* d_in, const int* in_sizes, int n_in,
                              void* d_out, int out_size, void* d_ws, size_t ws_size,
                              hipStream_t stream) {
    const float* x          = (const float*)d_in[0];
    const float* rsign_bias = (const float*)d_in[1];
    const float* W          = (const float*)d_in[2];
    const float* bn_gamma   = (const float*)d_in[3];
    const float* bn_beta    = (const float*)d_in[4];
    const float* bn_mean    = (const float*)d_in[5];
    const float* bn_var     = (const float*)d_in[6];
    const float* pr_slope   = (const float*)d_in[7];
    const float* pr_shift   = (const float*)d_in[8];
    const float* pr_bias    = (const float*)d_in[9];
    float* out = (float*)d_out;

    uint32_t* wbits = (uint32_t*)d_ws;
    float4*   params = (float4*)((char*)d_ws + 32768);

    precompute_kernel<<<dim3(C_), dim3(64), 0, stream>>>(
        W, bn_gamma, bn_beta, bn_mean, bn_var, pr_slope, pr_shift, pr_bias,
        wbits, params);

    // 784 = 12*64 + 16 -> 13 hw tiles of 64 (last partial), 64 batch images
    fused_kernel<<<dim3(13, B_), dim3(64, 8), 0, stream>>>(
        x, rsign_bias, wbits, params, out);
}

// Round 4
// 228.767 us; speedup vs baseline: 1.0917x; 1.0366x over previous
//
#include <hip/hip_runtime.h>
#include <cstdint>

#define C_    512
#define HW_   784
#define B_    64
#define BN_EPS 1e-5f

// Workspace layout:
//   [0, 32768)        : wbits   uint32[512][16]   (bit c%32 of word c/32 = 1 iff W[o][c] < 0)
//   [32768, 40960)    : params  float4[512]       {A, C0 = B2 - pr_shift, slope, bias}
//
// Math folding:
//   scale[o] = mean|W[o,:]| ; S = 512 - 2*popcount_xor ; y = scale*S
//   bn = gamma*(y-mean)*rsqrt(var+eps)+beta = A*S + B2,  A = gamma*scale*r, B2 = beta - gamma*mean*r
//   t  = bn + x - shift = A*S + (B2 - shift) + x
//   out = max(t,0) + slope*min(t,0) + bias   (branchless RPReLU)

__global__ __launch_bounds__(64) void precompute_kernel(
    const float* __restrict__ W,
    const float* __restrict__ bn_gamma, const float* __restrict__ bn_beta,
    const float* __restrict__ bn_mean,  const float* __restrict__ bn_var,
    const float* __restrict__ pr_slope, const float* __restrict__ pr_shift,
    const float* __restrict__ pr_bias,
    uint32_t* __restrict__ wbits, float4* __restrict__ params)
{
    const int o    = blockIdx.x;
    const int lane = threadIdx.x;
    const float* wrow = W + (size_t)o * C_;

    // mean(|W[o,:]|): stride-64 partials + wave-64 butterfly
    float s = 0.f;
    for (int c = lane; c < C_; c += 64) s += fabsf(wrow[c]);
    for (int off = 32; off > 0; off >>= 1) s += __shfl_down(s, off, 64);

    // sign bits: lanes 0..15 each pack one 32-bit word
    if (lane < 16) {
        uint32_t m = 0;
        const int cbase = lane * 32;
        #pragma unroll
        for (int t = 0; t < 32; ++t) {
            if (wrow[cbase + t] < 0.f) m |= (1u << t);
        }
        wbits[o * 16 + lane] = m;
    }

    if (lane == 0) {
        float scale = s * (1.0f / (float)C_);
        float r  = rsqrtf(bn_var[o] + BN_EPS);
        float A  = bn_gamma[o] * scale * r;
        float B2 = bn_beta[o] - bn_gamma[o] * bn_mean[o] * r;
        params[o] = make_float4(A, B2 - pr_shift[o], pr_slope[o], pr_bias[o]);
    }
}

// Block: (64 hw-lanes) x (16 waves). Wave jj binarizes channels [32jj,32jj+32)
// (exactly one bit-word) and computes outputs [32jj,32jj+32). 832 blocks of
// 16 waves; HW caps 2 blocks/CU (2048 thr) -> 8 waves/SIMD while resident
// (~3x the R3 residency, which was the latency-hiding bottleneck).
// __launch_bounds__(1024,8): VGPR cap 64 (R3 used 48 for a 2x bigger loop).
__global__ __launch_bounds__(1024, 8) void fused_kernel(
    const float* __restrict__ x, const float* __restrict__ rsign_bias,
    const uint32_t* __restrict__ wbits, const float4* __restrict__ params,
    float* __restrict__ out)
{
    // a-bit tile: 64 hw rows x 16 words, stride 17 -> 2-way bank aliasing (free)
    __shared__ uint32_t abits[64 * 17];

    const int i  = threadIdx.x;                                   // hw lane (0..63)
    const int jj = __builtin_amdgcn_readfirstlane(threadIdx.y);   // wave-uniform group (0..15)
    const int b  = blockIdx.y;
    const int hw = blockIdx.x * 64 + i;
    const bool valid = (hw < HW_);

    const float* xb = x + (size_t)b * C_ * HW_;
    const int c0 = jj * 32;                                       // wave-uniform

    // ---- Phase 1: binarize channels [c0, c0+32) -> one bit-word ----
    if (valid) {
        uint32_t m = 0;
        #pragma unroll
        for (int t = 0; t < 32; ++t) {
            const int c = c0 + t;                        // wave-uniform
            const float v = xb[(size_t)c * HW_ + hw] + rsign_bias[c];
            if (v < 0.f) m |= (1u << t);
        }
        abits[i * 17 + jj] = m;
    }
    __syncthreads();
    if (!valid) return;

    // ---- Phase 2: full 512-bit activation row from LDS ----
    uint32_t a[16];
    #pragma unroll
    for (int w = 0; w < 16; ++w) a[w] = abits[i * 17 + w];

    float* ob = out + (size_t)b * C_ * HW_;

    #pragma unroll
    for (int oo = 0; oo < 32; ++oo) {
        const int o = c0 + oo;                           // wave-uniform
        const uint32_t* wr = wbits + o * 16;
        int P = 0;
        #pragma unroll
        for (int w = 0; w < 16; ++w) P += __popc(a[w] ^ wr[w]);

        const float4 p = params[o];
        const float Sf = (float)(C_ - 2 * P);
        const float t = fmaf(p.x, Sf, p.y) + xb[(size_t)o * HW_ + hw];
        const float r = fmaf(p.z, fminf(t, 0.f), fmaxf(t, 0.f) + p.w);
        ob[(size_t)o * HW_ + hw] = r;
    }
}

extern "C" void kernel_launch(void* const* d_in, const int* in_sizes, int n_in,
                              void* d_out, int out_size, void* d_ws, size_t ws_size,
                              hipStream_t stream) {
    const float* x          = (const float*)d_in[0];
    const float* rsign_bias = (const float*)d_in[1];
    const float* W          = (const float*)d_in[2];
    const float* bn_gamma   = (const float*)d_in[3];
    const float* bn_beta    = (const float*)d_in[4];
    const float* bn_mean    = (const float*)d_in[5];
    const float* bn_var     = (const float*)d_in[6];
    const float* pr_slope   = (const float*)d_in[7];
    const float* pr_shift   = (const float*)d_in[8];
    const float* pr_bias    = (const float*)d_in[9];
    float* out = (float*)d_out;

    uint32_t* wbits = (uint32_t*)d_ws;
    float4*   params = (float4*)((char*)d_ws + 32768);

    precompute_kernel<<<dim3(C_), dim3(64), 0, stream>>>(
        W, bn_gamma, bn_beta, bn_mean, bn_var, pr_slope, pr_shift, pr_bias,
        wbits, params);

    // 784 = 12*64 + 16 -> 13 hw tiles of 64 (last partial), 64 batch images
    fused_kernel<<<dim3(13, B_), dim3(64, 16), 0, stream>>>(
        x, rsign_bias, wbits, params, out);
}